// Round 7
// baseline (401.242 us; speedup 1.0000x reference)
//
#include <hip/hip_runtime.h>

#define NBOND 96
#define HBS 158
#define NSTEP 288
#define NT 320

typedef float f4 __attribute__((ext_vector_type(4)));
#define Z4 ((f4){0.f, 0.f, 0.f, 0.f})
#define MK4(P, B) ((f4){(P)[(B)], (P)[(B)+1], (P)[(B)+2], (P)[(B)+3]})

__global__ __launch_bounds__(NT, 1)
void gcn_mp_kernel(const int* __restrict__ a2b,
                   const int* __restrict__ b2a,
                   const int* __restrict__ b2revb,
                   const float* __restrict__ f_bonds,
                   const float* __restrict__ bond_sum,
                   const float* __restrict__ W0,
                   const float* __restrict__ b0,
                   const float* __restrict__ W1, const float* __restrict__ b1,
                   const float* __restrict__ W2, const float* __restrict__ b2v,
                   const float* __restrict__ W3, const float* __restrict__ b3,
                   const float* __restrict__ W4, const float* __restrict__ b4,
                   float* __restrict__ out)
{
  const int m  = blockIdx.x;
  const int t  = threadIdx.x;
  const int og = t >> 3;       // 0..39  -> outputs og*4 .. og*4+3
  const int s  = t & 7;        // 0..7   -> k-slice [s*40, s*40+40)

  __shared__ __align__(16) float fb[NBOND * 160];   // rows padded to 160, pad cols = 0
  __shared__ __align__(16) float xv[2][320];        // double-buffered x = [fb[c] | bs]
  __shared__ int sDp[NSTEP];                        // d-1 | (alias_with_prev_c << 16)
  __shared__ int sRp[NSTEP];                        // rev | (alias_with_prev_c << 16)
  __shared__ __align__(16) float mpb[160];
  __shared__ float hb1[112], hb2[72], hb3[40];

  // ---- stage fb (pad cols >= 158 zeroed)
  for (int idx = t; idx < NBOND * 160; idx += NT) {
    int r = idx / 160, o = idx - r * 160;
    fb[idx] = (o < HBS) ? f_bonds[(m * NBOND + r) * HBS + o] : 0.f;
  }
  // ---- index + alias-flag precompute (addresses data-independent)
  if (t < NSTEP) {
    int i = t, c = i / 3, j = i - 3 * c;
    int a  = b2a[m * NBOND + c];
    int d  = a2b[(m * NBOND + a) * 3 + j] - 1;   // 0..95
    int rv = b2revb[m * NBOND + c];              // 0..95
    int cp = (i == 0) ? -1 : (i - 1) / 3;        // row written by previous step
    sDp[i] = d  | ((d  == cp) ? 0x10000 : 0);
    sRp[i] = rv | ((rv == cp) ? 0x10000 : 0);
  }

  // ---- W0: thread (og,s) holds rows og*4..+3, k in [s*40,s*40+40)
  // padded-K col base: k<160 -> col k ; k>=160 -> col k-2
  const int o0 = og * 4;
  const int cb = (s < 4) ? s * 40 : s * 40 - 2;
  const bool edge = (s == 3) || (s == 7);          // last 2 k's of the slice invalid
  const float* P0 = W0 + o0 * (2 * HBS) + cb;
  const float* P1 = W0 + (o0 + 1) * (2 * HBS) + cb;
  const float* P2 = W0 + ((o0 + 2 < HBS) ? o0 + 2 : HBS - 1) * (2 * HBS) + cb;
  const float* P3 = W0 + ((o0 + 3 < HBS) ? o0 + 3 : HBS - 1) * (2 * HBS) + cb;

#define DECLROW(R, P) \
  f4 w##R##0 = MK4(P, 0),  w##R##1 = MK4(P, 4),  w##R##2 = MK4(P, 8),  \
     w##R##3 = MK4(P, 12), w##R##4 = MK4(P, 16), w##R##5 = MK4(P, 20), \
     w##R##6 = MK4(P, 24), w##R##7 = MK4(P, 28), w##R##8 = MK4(P, 32); \
  f4 w##R##9 = (f4){(P)[36], (P)[37], edge ? 0.f : (P)[38], edge ? 0.f : (P)[39]};
  DECLROW(0, P0)
  DECLROW(1, P1)
  DECLROW(2, P2)
  DECLROW(3, P3)
#undef DECLROW
  if (o0 + 2 >= HBS) {   // og==39: rows 158,159 are padding
    w20 = Z4; w21 = Z4; w22 = Z4; w23 = Z4; w24 = Z4;
    w25 = Z4; w26 = Z4; w27 = Z4; w28 = Z4; w29 = Z4;
    w30 = Z4; w31 = Z4; w32 = Z4; w33 = Z4; w34 = Z4;
    w35 = Z4; w36 = Z4; w37 = Z4; w38 = Z4; w39 = Z4;
  }
  const float b0r0 = b0[o0];
  const float b0r1 = b0[o0 + 1];
  const float b0r2 = (o0 + 2 < HBS) ? b0[o0 + 2] : 0.f;
  const float b0r3 = (o0 + 3 < HBS) ? b0[o0 + 3] : 0.f;

  // ---- PARK the weights in AGPRs. The arch-VGPR pressure heuristic that
  // kept forcing in-loop reloads doesn't apply to AGPRs; VALU on gfx950 can
  // source AGPRs (unified file), worst case a v_accvgpr_read copy — either
  // way a register-file op, not a 200KB/step L1/L2 re-stream.
  asm volatile("" : "+a"(w00), "+a"(w01), "+a"(w02), "+a"(w03), "+a"(w04),
                    "+a"(w05), "+a"(w06), "+a"(w07), "+a"(w08), "+a"(w09));
  asm volatile("" : "+a"(w10), "+a"(w11), "+a"(w12), "+a"(w13), "+a"(w14),
                    "+a"(w15), "+a"(w16), "+a"(w17), "+a"(w18), "+a"(w19));
  asm volatile("" : "+a"(w20), "+a"(w21), "+a"(w22), "+a"(w23), "+a"(w24),
                    "+a"(w25), "+a"(w26), "+a"(w27), "+a"(w28), "+a"(w29));
  asm volatile("" : "+a"(w30), "+a"(w31), "+a"(w32), "+a"(w33), "+a"(w34),
                    "+a"(w35), "+a"(w36), "+a"(w37), "+a"(w38), "+a"(w39));

  __syncthreads();

  // ---- build x for step 0 (all-original fb state)
  if (t < 160) {
    int d0 = sDp[0] & 0xFFFF, r0 = sRp[0] & 0xFFFF;
    xv[0][t] = fb[t];
    float bsv = ((t < HBS) ? bond_sum[m * HBS + t] : 0.f)
              + fb[d0 * 160 + t] - fb[r0 * 160 + t];
    xv[0][160 + t] = bsv;
  }
  __syncthreads();

  float cs0 = 0.f, cs1 = 0.f, cs2 = 0.f, cs3 = 0.f;
  int p = 0;

#pragma unroll 1
  for (int i = 0; i < NSTEP; ++i) {
    const int c  = i / 3;
    const int j  = i - 3 * c;
    const int i1 = i + 1;
    const int c1 = i1 / 3;
    const int j1 = i1 - 3 * c1;
    const bool hn = (i1 < NSTEP);

    const f4* XP = (const f4*)(&xv[p][s * 40]);
    f4 xa = XP[0], xb = XP[1], xc = XP[2], xd = XP[3];

    // ---- early loads for next-step x prep
    f4 nxr = Z4;
    float2 dd = make_float2(0.f, 0.f), rr = make_float2(0.f, 0.f), bo = make_float2(0.f, 0.f);
    int aD = 0, aR = 0, e0 = 0;
    if (hn) {
      if (s == 1 && j1 == 0) {
        const float* q = &fb[c1 * 160 + og * 4];   // pristine row: race-free pre-barrier
        nxr = (f4){q[0], q[1], q[2], q[3]};
      }
      if (s >= 2 && s <= 3) {
        const int pd = sDp[i1], pr = sRp[i1];
        const int d  = pd & 0xFFFF;  aD = pd >> 16;
        const int rv = pr & 0xFFFF;  aR = pr >> 16;
        e0 = og * 4 + (s - 2) * 2;
        dd = *(const float2*)(&fb[d  * 160 + e0]); // stale-if-alias: select below
        rr = *(const float2*)(&fb[rv * 160 + e0]);
        bo = *(const float2*)(&xv[p][160 + e0]);
      }
    }

    // ---- 160 FMAs, fully static indexing on AGPR-parked weights
    float a0 = 0.f, a1 = 0.f, a2 = 0.f, a3 = 0.f;
#define QSTEP(Q, XX) \
    a0 = fmaf(w0##Q[0], XX[0], a0); a1 = fmaf(w1##Q[0], XX[0], a1); \
    a2 = fmaf(w2##Q[0], XX[0], a2); a3 = fmaf(w3##Q[0], XX[0], a3); \
    a0 = fmaf(w0##Q[1], XX[1], a0); a1 = fmaf(w1##Q[1], XX[1], a1); \
    a2 = fmaf(w2##Q[1], XX[1], a2); a3 = fmaf(w3##Q[1], XX[1], a3); \
    a0 = fmaf(w0##Q[2], XX[2], a0); a1 = fmaf(w1##Q[2], XX[2], a1); \
    a2 = fmaf(w2##Q[2], XX[2], a2); a3 = fmaf(w3##Q[2], XX[2], a3); \
    a0 = fmaf(w0##Q[3], XX[3], a0); a1 = fmaf(w1##Q[3], XX[3], a1); \
    a2 = fmaf(w2##Q[3], XX[3], a2); a3 = fmaf(w3##Q[3], XX[3], a3);
    QSTEP(0, xa) xa = XP[4];
    QSTEP(1, xb) xb = XP[5];
    QSTEP(2, xc) xc = XP[6];
    QSTEP(3, xd) xd = XP[7];
    QSTEP(4, xa) xa = XP[8];
    QSTEP(5, xb) xb = XP[9];
    QSTEP(6, xc)
    QSTEP(7, xd)
    QSTEP(8, xa)
    QSTEP(9, xb)
#undef QSTEP

    // ---- butterfly reduce over the 8 k-slices: every lane ends with full nf
    a0 += __shfl_xor(a0, 1); a0 += __shfl_xor(a0, 2); a0 += __shfl_xor(a0, 4);
    a1 += __shfl_xor(a1, 1); a1 += __shfl_xor(a1, 2); a1 += __shfl_xor(a1, 4);
    a2 += __shfl_xor(a2, 1); a2 += __shfl_xor(a2, 2); a2 += __shfl_xor(a2, 4);
    a3 += __shfl_xor(a3, 1); a3 += __shfl_xor(a3, 2); a3 += __shfl_xor(a3, 4);
    a0 += b0r0; a1 += b0r1; a2 += b0r2; a3 += b0r3;

    // ---- writes (roles by s); single barrier covers everything
    if (s == 0) {
      *(float4*)(&fb[c * 160 + og * 4]) = make_float4(a0, a1, a2, a3);
    }
    if (hn) {
      if (s == 1) {
        float4 wv = (j1 == 0) ? make_float4(nxr[0], nxr[1], nxr[2], nxr[3])
                              : make_float4(a0, a1, a2, a3);
        *(float4*)(&xv[p ^ 1][og * 4]) = wv;       // next x, first half
      }
      if (s >= 2 && s <= 3) {
        float sA = (s == 2) ? a0 : a2;             // nf at elements e0, e0+1
        float sB = (s == 2) ? a1 : a3;
        float vd0 = aD ? sA : dd.x;
        float vd1 = aD ? sB : dd.y;
        float vr0 = aR ? sA : rr.x;
        float vr1 = aR ? sB : rr.y;
        *(float2*)(&xv[p ^ 1][160 + e0]) =
            make_float2(bo.x + vd0 - vr0, bo.y + vd1 - vr1);   // next bs
      }
    }
    if (j == 2) { cs0 += a0; cs1 += a1; cs2 += a2; cs3 += a3; }

    p ^= 1;
    __syncthreads();
  }

  // ---- mp = column sums (accumulated in registers at j==2 steps)
  if (s == 0) {
    *(float4*)(&mpb[og * 4]) = make_float4(cs0, cs1, cs2, cs3);  // pads (158,159) are 0
  }
  __syncthreads();

  // ---- tiny MLP: 158 -> 110 (no relu) -> 70 (relu) -> 35 (relu) -> 1
  if (t < 110) {
    float acc = b1[t];
    for (int k = 0; k < HBS; ++k) acc = fmaf(mpb[k], W1[t * HBS + k], acc);
    hb1[t] = acc;
  }
  __syncthreads();
  if (t < 70) {
    float acc = b2v[t];
    for (int k = 0; k < 110; ++k) acc = fmaf(hb1[k], W2[t * 110 + k], acc);
    hb2[t] = fmaxf(acc, 0.f);
  }
  __syncthreads();
  if (t < 35) {
    float acc = b3[t];
    for (int k = 0; k < 70; ++k) acc = fmaf(hb2[k], W3[t * 70 + k], acc);
    hb3[t] = fmaxf(acc, 0.f);
  }
  __syncthreads();
  if (t == 0) {
    float acc = b4[0];
    for (int k = 0; k < 35; ++k) acc = fmaf(hb3[k], W4[k], acc);
    out[m] = acc;
  }
}

extern "C" void kernel_launch(void* const* d_in, const int* in_sizes, int n_in,
                              void* d_out, int out_size, void* d_ws, size_t ws_size,
                              hipStream_t stream)
{
  const int*   a2b      = (const int*)d_in[0];
  const int*   b2a      = (const int*)d_in[1];
  const int*   b2revb   = (const int*)d_in[2];
  const float* f_bonds  = (const float*)d_in[3];
  /* d_in[4] = f_atoms_ (unused by forward) */
  const float* bond_sum = (const float*)d_in[5];
  const float* W0 = (const float*)d_in[6];
  const float* b0 = (const float*)d_in[7];
  const float* W1 = (const float*)d_in[8];
  const float* b1 = (const float*)d_in[9];
  const float* W2 = (const float*)d_in[10];
  const float* b2 = (const float*)d_in[11];
  const float* W3 = (const float*)d_in[12];
  const float* b3 = (const float*)d_in[13];
  const float* W4 = (const float*)d_in[14];
  const float* b4 = (const float*)d_in[15];

  gcn_mp_kernel<<<dim3(96), dim3(NT), 0, stream>>>(
      a2b, b2a, b2revb, f_bonds, bond_sum,
      W0, b0, W1, b1, W2, b2, W3, b3, W4, b4,
      (float*)d_out);
}

// Round 8
// 342.975 us; speedup vs baseline: 1.1699x; 1.1699x over previous
//
#include <hip/hip_runtime.h>

#define NBOND 96
#define HBS 158
#define NSTEP 288
#define NT 256

typedef float f4 __attribute__((ext_vector_type(4)));
#define Z4 ((f4){0.f, 0.f, 0.f, 0.f})
#define MK4(P, B) ((f4){(P)[(B)], (P)[(B)+1], (P)[(B)+2], (P)[(B)+3]})

__global__ __launch_bounds__(NT, 1)
void gcn_mp_kernel(const int* __restrict__ a2b,
                   const int* __restrict__ b2a,
                   const int* __restrict__ b2revb,
                   const float* __restrict__ f_bonds,
                   const float* __restrict__ bond_sum,
                   const float* __restrict__ W0,
                   const float* __restrict__ b0,
                   const float* __restrict__ W1, const float* __restrict__ b1,
                   const float* __restrict__ W2, const float* __restrict__ b2v,
                   const float* __restrict__ W3, const float* __restrict__ b3,
                   const float* __restrict__ W4, const float* __restrict__ b4,
                   float* __restrict__ out)
{
  const int m  = blockIdx.x;
  const int t  = threadIdx.x;
  const int og = t >> 3;       // 0..31 -> output cols og, og+32, og+64, og+96, og+128
  const int s  = t & 7;        // 0..7  -> k-slice [s*40, s*40+40) of padded K=320

  __shared__ __align__(16) float fb[NBOND * 160];   // rows padded to 160, pad cols = 0
  __shared__ __align__(16) float xv[2][320];        // double-buffered x = [fb[c] | bs]
  __shared__ int sDp[NSTEP];                        // d-1 | (alias_with_prev_c << 16)
  __shared__ int sRp[NSTEP];                        // rev | (alias_with_prev_c << 16)
  __shared__ __align__(16) float mpb[160];
  __shared__ float hb1[112], hb2[72], hb3[40];
  // Occupancy clamp: total LDS ~84KB > 80KB -> only 1 block/CU feasible ->
  // RA's occupancy-with-LDS = 1 wave/EU (NT=256) -> VGPR budget is maximal.
  // volatile store cannot be DCE'd, so the array survives.
  __shared__ float lds_pad[4096];
  {
    volatile float* vp = lds_pad;
    vp[t] = 0.f;
  }

  // ---- stage fb (pad cols >= 158 zeroed)
  for (int idx = t; idx < NBOND * 160; idx += NT) {
    int r = idx / 160, o = idx - r * 160;
    fb[idx] = (o < HBS) ? f_bonds[(m * NBOND + r) * HBS + o] : 0.f;
  }
  // ---- index + alias-flag precompute (addresses data-independent)
  for (int i = t; i < NSTEP; i += NT) {
    int c = i / 3, j = i - 3 * c;
    int a  = b2a[m * NBOND + c];
    int d  = a2b[(m * NBOND + a) * 3 + j] - 1;   // 0..95
    int rv = b2revb[m * NBOND + c];              // 0..95
    int cp = (i == 0) ? -1 : (i - 1) / 3;        // row written by previous step
    sDp[i] = d  | ((d  == cp) ? 0x10000 : 0);
    sRp[i] = rv | ((rv == cp) ? 0x10000 : 0);
  }

  // ---- W0 in 50 named f4 registers: thread (og,s) holds output rows og+32r
  // (r=0..4), k-slice [s*40, s*40+40). padded-K col: k<160 -> k ; k>=160 -> k-2.
  const int cb = (s < 4) ? s * 40 : s * 40 - 2;
  const bool edge = (s == 3) || (s == 7);          // last 2 k's of slice invalid
  const float* P0 = W0 + (og      ) * (2 * HBS) + cb;
  const float* P1 = W0 + (og + 32 ) * (2 * HBS) + cb;
  const float* P2 = W0 + (og + 64 ) * (2 * HBS) + cb;
  const float* P3 = W0 + (og + 96 ) * (2 * HBS) + cb;
  const int o4 = (og + 128 < HBS) ? og + 128 : HBS - 1;   // clamp pad rows
  const float* P4 = W0 + o4 * (2 * HBS) + cb;

#define DECLROW(R, P) \
  f4 w##R##0 = MK4(P, 0),  w##R##1 = MK4(P, 4),  w##R##2 = MK4(P, 8),  \
     w##R##3 = MK4(P, 12), w##R##4 = MK4(P, 16), w##R##5 = MK4(P, 20), \
     w##R##6 = MK4(P, 24), w##R##7 = MK4(P, 28), w##R##8 = MK4(P, 32); \
  f4 w##R##9 = (f4){(P)[36], (P)[37], edge ? 0.f : (P)[38], edge ? 0.f : (P)[39]};
  DECLROW(0, P0)
  DECLROW(1, P1)
  DECLROW(2, P2)
  DECLROW(3, P3)
  DECLROW(4, P4)
#undef DECLROW
  if (og + 128 >= HBS) {   // output cols 158/159 are padding -> zero weights
    w40 = Z4; w41 = Z4; w42 = Z4; w43 = Z4; w44 = Z4;
    w45 = Z4; w46 = Z4; w47 = Z4; w48 = Z4; w49 = Z4;
  }
  const float b0r0 = b0[og];
  const float b0r1 = b0[og + 32];
  const float b0r2 = b0[og + 64];
  const float b0r3 = b0[og + 96];
  const float b0r4 = (og + 128 < HBS) ? b0[og + 128] : 0.f;

  // ---- pin the weights (opaque defs: not remat-able, not sinkable)
  asm volatile("" : "+v"(w00), "+v"(w01), "+v"(w02), "+v"(w03), "+v"(w04),
                    "+v"(w05), "+v"(w06), "+v"(w07), "+v"(w08), "+v"(w09));
  asm volatile("" : "+v"(w10), "+v"(w11), "+v"(w12), "+v"(w13), "+v"(w14),
                    "+v"(w15), "+v"(w16), "+v"(w17), "+v"(w18), "+v"(w19));
  asm volatile("" : "+v"(w20), "+v"(w21), "+v"(w22), "+v"(w23), "+v"(w24),
                    "+v"(w25), "+v"(w26), "+v"(w27), "+v"(w28), "+v"(w29));
  asm volatile("" : "+v"(w30), "+v"(w31), "+v"(w32), "+v"(w33), "+v"(w34),
                    "+v"(w35), "+v"(w36), "+v"(w37), "+v"(w38), "+v"(w39));
  asm volatile("" : "+v"(w40), "+v"(w41), "+v"(w42), "+v"(w43), "+v"(w44),
                    "+v"(w45), "+v"(w46), "+v"(w47), "+v"(w48), "+v"(w49));

  __syncthreads();

  // ---- build x for step 0 (all-original fb state)
  if (t < 160) {
    int d0 = sDp[0] & 0xFFFF, r0 = sRp[0] & 0xFFFF;
    xv[0][t] = fb[t];
    float bsv = ((t < HBS) ? bond_sum[m * HBS + t] : 0.f)
              + fb[d0 * 160 + t] - fb[r0 * 160 + t];
    xv[0][160 + t] = bsv;
  }
  __syncthreads();

  float cs0 = 0.f, cs1 = 0.f, cs2 = 0.f, cs3 = 0.f, cs4 = 0.f;
  int p = 0;

#pragma unroll 1
  for (int i = 0; i < NSTEP; ++i) {
    const int c  = i / 3;
    const int j  = i - 3 * c;
    const int i1 = i + 1;
    const int c1 = i1 / 3;
    const int j1 = i1 - 3 * c1;
    const bool hn = (i1 < NSTEP);

    const f4* XP = (const f4*)(&xv[p][s * 40]);
    f4 xa = XP[0], xb = XP[1], xc = XP[2], xd = XP[3];

    // ---- early loads for next-step x prep (roles by s)
    float nx0 = 0.f, nx1 = 0.f, nx2 = 0.f, nx3 = 0.f, nx4 = 0.f;
    float dd0 = 0.f, dd1 = 0.f, dd2 = 0.f, dd3 = 0.f, dd4 = 0.f;
    float rr0 = 0.f, rr1 = 0.f, rr2 = 0.f, rr3 = 0.f, rr4 = 0.f;
    float bo0 = 0.f, bo1 = 0.f, bo2 = 0.f, bo3 = 0.f, bo4 = 0.f;
    int aD = 0, aR = 0;
    if (hn) {
      if (s == 1 && j1 == 0) {
        // row c1 pristine until its own steps -> race-free pre-barrier read
        const float* q = &fb[c1 * 160 + og];
        nx0 = q[0]; nx1 = q[32]; nx2 = q[64]; nx3 = q[96]; nx4 = q[128];
      }
      if (s == 2) {
        const int pd = sDp[i1], pr = sRp[i1];
        const int d  = pd & 0xFFFF;  aD = pd >> 16;
        const int rv = pr & 0xFFFF;  aR = pr >> 16;
        const float* qd = &fb[d  * 160 + og];
        const float* qr = &fb[rv * 160 + og];
        const float* qb = &xv[p][160 + og];
        dd0 = qd[0]; dd1 = qd[32]; dd2 = qd[64]; dd3 = qd[96]; dd4 = qd[128];
        rr0 = qr[0]; rr1 = qr[32]; rr2 = qr[64]; rr3 = qr[96]; rr4 = qr[128];
        bo0 = qb[0]; bo1 = qb[32]; bo2 = qb[64]; bo3 = qb[96]; bo4 = qb[128];
      }
    }

    // ---- 200 FMAs: 5 outputs x 40-k slice, fully static on pinned regs
    float a0 = 0.f, a1 = 0.f, a2 = 0.f, a3 = 0.f, a4 = 0.f;
#define QSTEP(Q, XX) \
    a0 = fmaf(w0##Q[0], XX[0], a0); a1 = fmaf(w1##Q[0], XX[0], a1); \
    a2 = fmaf(w2##Q[0], XX[0], a2); a3 = fmaf(w3##Q[0], XX[0], a3); \
    a4 = fmaf(w4##Q[0], XX[0], a4); \
    a0 = fmaf(w0##Q[1], XX[1], a0); a1 = fmaf(w1##Q[1], XX[1], a1); \
    a2 = fmaf(w2##Q[1], XX[1], a2); a3 = fmaf(w3##Q[1], XX[1], a3); \
    a4 = fmaf(w4##Q[1], XX[1], a4); \
    a0 = fmaf(w0##Q[2], XX[2], a0); a1 = fmaf(w1##Q[2], XX[2], a1); \
    a2 = fmaf(w2##Q[2], XX[2], a2); a3 = fmaf(w3##Q[2], XX[2], a3); \
    a4 = fmaf(w4##Q[2], XX[2], a4); \
    a0 = fmaf(w0##Q[3], XX[3], a0); a1 = fmaf(w1##Q[3], XX[3], a1); \
    a2 = fmaf(w2##Q[3], XX[3], a2); a3 = fmaf(w3##Q[3], XX[3], a3); \
    a4 = fmaf(w4##Q[3], XX[3], a4);
    QSTEP(0, xa) xa = XP[4];
    QSTEP(1, xb) xb = XP[5];
    QSTEP(2, xc) xc = XP[6];
    QSTEP(3, xd) xd = XP[7];
    QSTEP(4, xa) xa = XP[8];
    QSTEP(5, xb) xb = XP[9];
    QSTEP(6, xc)
    QSTEP(7, xd)
    QSTEP(8, xa)
    QSTEP(9, xb)
#undef QSTEP

    // ---- butterfly reduce over 8 k-slices: every lane ends with full nf
    a0 += __shfl_xor(a0, 1); a0 += __shfl_xor(a0, 2); a0 += __shfl_xor(a0, 4);
    a1 += __shfl_xor(a1, 1); a1 += __shfl_xor(a1, 2); a1 += __shfl_xor(a1, 4);
    a2 += __shfl_xor(a2, 1); a2 += __shfl_xor(a2, 2); a2 += __shfl_xor(a2, 4);
    a3 += __shfl_xor(a3, 1); a3 += __shfl_xor(a3, 2); a3 += __shfl_xor(a3, 4);
    a4 += __shfl_xor(a4, 1); a4 += __shfl_xor(a4, 2); a4 += __shfl_xor(a4, 4);
    a0 += b0r0; a1 += b0r1; a2 += b0r2; a3 += b0r3; a4 += b0r4;

    // ---- writes (roles by s); single barrier covers everything
    if (s == 0) {
      float* q = &fb[c * 160 + og];
      q[0] = a0; q[32] = a1; q[64] = a2; q[96] = a3; q[128] = a4;
    }
    if (hn) {
      const int pn = p ^ 1;
      if (s == 1) {
        float* q = &xv[pn][og];
        q[0]   = (j1 == 0) ? nx0 : a0;
        q[32]  = (j1 == 0) ? nx1 : a1;
        q[64]  = (j1 == 0) ? nx2 : a2;
        q[96]  = (j1 == 0) ? nx3 : a3;
        q[128] = (j1 == 0) ? nx4 : a4;
      }
      if (s == 2) {
        float* q = &xv[pn][160 + og];
        q[0]   = bo0 + (aD ? a0 : dd0) - (aR ? a0 : rr0);
        q[32]  = bo1 + (aD ? a1 : dd1) - (aR ? a1 : rr1);
        q[64]  = bo2 + (aD ? a2 : dd2) - (aR ? a2 : rr2);
        q[96]  = bo3 + (aD ? a3 : dd3) - (aR ? a3 : rr3);
        q[128] = bo4 + (aD ? a4 : dd4) - (aR ? a4 : rr4);
      }
    }
    if (j == 2) { cs0 += a0; cs1 += a1; cs2 += a2; cs3 += a3; cs4 += a4; }

    p ^= 1;
    __syncthreads();
  }

  // ---- mp = column sums (accumulated in registers at j==2 steps)
  if (s == 4) {
    float* q = &mpb[og];
    q[0] = cs0; q[32] = cs1; q[64] = cs2; q[96] = cs3; q[128] = cs4;  // pads = 0
  }
  __syncthreads();

  // ---- tiny MLP: 158 -> 110 (no relu) -> 70 (relu) -> 35 (relu) -> 1
  if (t < 110) {
    float acc = b1[t];
    for (int k = 0; k < HBS; ++k) acc = fmaf(mpb[k], W1[t * HBS + k], acc);
    hb1[t] = acc;
  }
  __syncthreads();
  if (t < 70) {
    float acc = b2v[t];
    for (int k = 0; k < 110; ++k) acc = fmaf(hb1[k], W2[t * 110 + k], acc);
    hb2[t] = fmaxf(acc, 0.f);
  }
  __syncthreads();
  if (t < 35) {
    float acc = b3[t];
    for (int k = 0; k < 70; ++k) acc = fmaf(hb2[k], W3[t * 70 + k], acc);
    hb3[t] = fmaxf(acc, 0.f);
  }
  __syncthreads();
  if (t == 0) {
    float acc = b4[0];
    for (int k = 0; k < 35; ++k) acc = fmaf(hb3[k], W4[k], acc);
    out[m] = acc;
  }
}

extern "C" void kernel_launch(void* const* d_in, const int* in_sizes, int n_in,
                              void* d_out, int out_size, void* d_ws, size_t ws_size,
                              hipStream_t stream)
{
  const int*   a2b      = (const int*)d_in[0];
  const int*   b2a      = (const int*)d_in[1];
  const int*   b2revb   = (const int*)d_in[2];
  const float* f_bonds  = (const float*)d_in[3];
  /* d_in[4] = f_atoms_ (unused by forward) */
  const float* bond_sum = (const float*)d_in[5];
  const float* W0 = (const float*)d_in[6];
  const float* b0 = (const float*)d_in[7];
  const float* W1 = (const float*)d_in[8];
  const float* b1 = (const float*)d_in[9];
  const float* W2 = (const float*)d_in[10];
  const float* b2 = (const float*)d_in[11];
  const float* W3 = (const float*)d_in[12];
  const float* b3 = (const float*)d_in[13];
  const float* W4 = (const float*)d_in[14];
  const float* b4 = (const float*)d_in[15];

  gcn_mp_kernel<<<dim3(96), dim3(NT), 0, stream>>>(
      a2b, b2a, b2revb, f_bonds, bond_sum,
      W0, b0, W1, b1, W2, b2, W3, b3, W4, b4,
      (float*)d_out);
}